// Round 1
// baseline (81.015 us; speedup 1.0000x reference)
//
#include <hip/hip_runtime.h>
#include <hip/hip_bf16.h>
#include <stdint.h>

typedef __attribute__((ext_vector_type(8))) short bf16x8;
typedef __attribute__((ext_vector_type(4))) float f32x4;

__device__ __forceinline__ short f2bf(float x) {
    uint32_t u = __builtin_bit_cast(uint32_t, x);
    uint32_t r = (u + 0x7FFFu + ((u >> 16) & 1u)) >> 16;
    return (short)r;
}

// ---------------------------------------------------------------------------
// Kernel C: repack Wq (1024x48 f32) into bf16 B-fragment layout:
// wfrag[((ks*3+nf)*64 + lane)*8 + j] = Wq[k][n], k=ks*32+(lane>>4)*8+j, n=nf*16+(lane&15)
// ---------------------------------------------------------------------------
__global__ __launch_bounds__(256) void prep_wfrag(const float* __restrict__ Wq,
                                                  short* __restrict__ wfrag) {
    int idx = blockIdx.x * 256 + threadIdx.x;   // 0..49151
    int j    = idx & 7;
    int lane = (idx >> 3) & 63;
    int grp  = idx >> 9;          // ks*3+nf, 0..95
    int nf   = grp % 3;
    int ks   = grp / 3;
    int k = ks * 32 + ((lane >> 4) << 3) + j;
    int n = nf * 16 + (lane & 15);
    wfrag[idx] = f2bf(Wq[k * 48 + n]);
}

// ---------------------------------------------------------------------------
// Kernel A: qk = Q @ Wq + bq  (M=32768, N=48, K=1024), MFMA 16x16x32 bf16.
// Each wave: 16 rows x 48 cols. A-frags read straight from global f32.
// Epilogue scatter-stores bf16 weights into wgt[b][h][k][d].
// ---------------------------------------------------------------------------
__global__ __launch_bounds__(256) void qk_gemm(const float* __restrict__ Q,
                                               const short* __restrict__ wfrag,
                                               const float* __restrict__ bq,
                                               short* __restrict__ wgt) {
    const int l  = threadIdx.x & 63;
    const int w  = threadIdx.x >> 6;
    const int lr = l & 15;
    const int lk = l >> 4;
    const int row0 = blockIdx.x * 64 + w * 16;   // this wave's 16 rows

    f32x4 acc[3];
    acc[0] = (f32x4){0.f, 0.f, 0.f, 0.f};
    acc[1] = acc[0];
    acc[2] = acc[0];

    const float* qbase = Q + (size_t)(row0 + lr) * 1024 + lk * 8;

    #pragma unroll 4
    for (int ks = 0; ks < 32; ++ks) {
        const float* p = qbase + ks * 32;
        f32x4 q0 = *(const f32x4*)p;
        f32x4 q1 = *(const f32x4*)(p + 4);
        bf16x8 a;
        a[0] = f2bf(q0[0]); a[1] = f2bf(q0[1]); a[2] = f2bf(q0[2]); a[3] = f2bf(q0[3]);
        a[4] = f2bf(q1[0]); a[5] = f2bf(q1[1]); a[6] = f2bf(q1[2]); a[7] = f2bf(q1[3]);
        const bf16x8* wp = (const bf16x8*)(wfrag + (size_t)ks * 1536 + l * 8);
        acc[0] = __builtin_amdgcn_mfma_f32_16x16x32_bf16(a, wp[0],   acc[0], 0, 0, 0);
        acc[1] = __builtin_amdgcn_mfma_f32_16x16x32_bf16(a, wp[64],  acc[1], 0, 0, 0);
        acc[2] = __builtin_amdgcn_mfma_f32_16x16x32_bf16(a, wp[128], acc[2], 0, 0, 0);
    }

    // C frag: col n = nf*16+lr, row = row0 + lk*4 + r
    #pragma unroll
    for (int nf = 0; nf < 3; ++nf) {
        int n = nf * 16 + lr;
        float bias = bq[n];
        int t  = n / 3;
        int kk = n - t * 3;
        #pragma unroll
        for (int r = 0; r < 4; ++r) {
            int row = row0 + lk * 4 + r;
            int b   = row >> 10;
            int rb  = row & 1023;
            int h   = rb >> 6;
            int sp  = rb & 63;
            int d   = sp * 16 + t;
            wgt[((((b << 4) + h) * 3 + kk) << 10) + d] = f2bf(acc[nf][r] + bias);
        }
    }
}

// ---------------------------------------------------------------------------
// Kernel B: per-batch conv-as-GEMM  out[h,s] = sum_{k,d} wgt[b,h,k,d]*key[b,s+k-1,d]
// M=16 (h), N=128 s-tile (16/wave, 8 waves), K'=3072 chunked (dc=128 f32->bf16 LDS).
// LDS row stride 272B -> ds_read_b128 granule shift 1/row, bank-pipelined.
// ---------------------------------------------------------------------------
__global__ __launch_bounds__(512) void conv_mfma(const float* __restrict__ Key,
                                                 const short* __restrict__ wgt,
                                                 float* __restrict__ out) {
    __shared__ short klds[130][136];   // 35360 B
    const int b   = blockIdx.x >> 3;
    const int s0  = (blockIdx.x & 7) * 128;
    const int tid = threadIdx.x;
    const int l   = tid & 63;
    const int w   = tid >> 6;          // 0..7
    const int lr  = l & 15;
    const int lk  = l >> 4;

    f32x4 acc = (f32x4){0.f, 0.f, 0.f, 0.f};

    const float* keyB = Key + ((size_t)b << 20);
    const short* wgtB = wgt + (size_t)b * 49152;

    for (int dc = 0; dc < 1024; dc += 128) {
        __syncthreads();
        // stage 130 rows x 128 cols of keys (f32 -> bf16)
        #pragma unroll
        for (int it = 0; it < 5; ++it) {
            int idx = it * 512 + tid;            // 0..2079 = 130*16
            if (idx < 130 * 16) {
                int row = idx >> 4;
                int oct = (idx & 15) << 3;       // 0..120 step 8 (shorts)
                int srow = s0 - 1 + row;
                f32x4 v0 = (f32x4){0.f, 0.f, 0.f, 0.f};
                f32x4 v1 = v0;
                if (srow >= 0 && srow < 1024) {
                    const float* p = keyB + ((size_t)srow << 10) + dc + oct;
                    v0 = *(const f32x4*)p;
                    v1 = *(const f32x4*)(p + 4);
                }
                bf16x8 bv;
                bv[0] = f2bf(v0[0]); bv[1] = f2bf(v0[1]); bv[2] = f2bf(v0[2]); bv[3] = f2bf(v0[3]);
                bv[4] = f2bf(v1[0]); bv[5] = f2bf(v1[1]); bv[6] = f2bf(v1[2]); bv[7] = f2bf(v1[3]);
                *(bf16x8*)(&klds[row][oct]) = bv;
            }
        }
        __syncthreads();

        #pragma unroll
        for (int k = 0; k < 3; ++k) {
            const short* wk = wgtB + ((lr * 3 + k) << 10) + dc + lk * 8;
            #pragma unroll
            for (int dstep = 0; dstep < 4; ++dstep) {
                bf16x8 a  = *(const bf16x8*)(wk + dstep * 32);
                bf16x8 kv = *(const bf16x8*)(&klds[w * 16 + lr + k][dstep * 32 + lk * 8]);
                acc = __builtin_amdgcn_mfma_f32_16x16x32_bf16(a, kv, acc, 0, 0, 0);
            }
        }
    }

    // C frag: col = s index (lr), row = h = lk*4 + r
    #pragma unroll
    for (int r = 0; r < 4; ++r) {
        int h = lk * 4 + r;
        int s = s0 + w * 16 + lr;
        out[(((b << 4) + h) << 10) + s] = acc[r];
    }
}

extern "C" void kernel_launch(void* const* d_in, const int* in_sizes, int n_in,
                              void* d_out, int out_size, void* d_ws, size_t ws_size,
                              hipStream_t stream) {
    const float* Q  = (const float*)d_in[0];
    const float* K  = (const float*)d_in[1];
    const float* Wq = (const float*)d_in[4];
    const float* bq = (const float*)d_in[5];
    float* outp = (float*)d_out;

    short* wfrag = (short*)d_ws;                      // 98304 B
    short* wgt   = (short*)((char*)d_ws + 98304);     // 3145728 B

    hipLaunchKernelGGL(prep_wfrag, dim3(192), dim3(256), 0, stream, Wq, wfrag);
    hipLaunchKernelGGL(qk_gemm,    dim3(512), dim3(256), 0, stream, Q, wfrag, bq, wgt);
    hipLaunchKernelGGL(conv_mfma,  dim3(256), dim3(512), 0, stream, K, wgt, outp);
}